// Round 2
// baseline (1727.073 us; speedup 1.0000x reference)
//
#include <hip/hip_runtime.h>
#include <hip/hip_bf16.h>
#include <cstdint>
#include <cstddef>
#include <type_traits>

// KAN GLU expert:
//   h = kan(x;w1) * kan(x;w2);  out = kan(h;w3)
// kan(x;W) == [silu(x_i), B0..B7(x_i)]_i  @  [base_w | spline_w]^T
// -> bf16 MFMA GEMMs with K expanded 9x.
//
// Workspace (adaptive, fits 293.6 MB; uses 360.7 MB if available for f32 H):
//   region0 [0, 151MB):       W12 (8192x9216 bf16)  -> after GEMM1: A3 chunk
//                             (1024x36864 bf16, 75.5MB) + splitK partials
//                             (8x1024x1024 f32, 33.5MB)
//   region1 [151, 226.5MB):   A1 (4096x9216 bf16)   -> after GEMM1: W3
//   region2 [226.5MB, ...):   H  (4096x8192) f32 (134MB) or bf16 (67MB)

#define D_MODEL 1024
#define D_FF    4096
#define NTOK    4096            // 2*2048 rows
#define NC      9               // silu + 8 spline bases
#define K1      (D_MODEL * NC)  // 9216
#define K3      (D_FF * NC)     // 36864
#define SPLITK  8
#define CHUNK   1024            // tokens per GEMM2 chunk

typedef __attribute__((ext_vector_type(8))) short bf16x8;
typedef __attribute__((ext_vector_type(4))) float f32x4;

// ---------------------------------------------------------------------------
// 9-feature generator: silu(x) and the 8 cubic B-spline bases on the uniform
// grid t_m = 0.4*m - 2.2 (m=0..11), exactly the reference's Cox-de Boor.
// ---------------------------------------------------------------------------
__device__ __forceinline__ void kan_feat(float x, __hip_bfloat16* dst) {
  float s = x / (1.0f + __expf(-x));
  float B[11];
#pragma unroll
  for (int j = 0; j < 11; ++j) {
    float gj = -2.2f + 0.4f * j;
    B[j] = (x >= gj && x < gj + 0.4f) ? 1.0f : 0.0f;
  }
#pragma unroll
  for (int p = 1; p <= 3; ++p) {
    float inv = 1.0f / (0.4f * p);
#pragma unroll
    for (int i = 0; i + p < 11; ++i) {
      float gi = -2.2f + 0.4f * i;
      B[i] = (x - gi) * inv * B[i] + ((gi + 0.4f + 0.4f * p) - x) * inv * B[i + 1];
    }
  }
  dst[0] = __float2bfloat16(s);
#pragma unroll
  for (int c = 0; c < 8; ++c) dst[1 + c] = __float2bfloat16(B[c]);
}

// ---------------------------------------------------------------------------
// Pack [base_w (out,in) | spline_w (out,in,8)] f32 -> bf16 W(out, in*9),
// K-layout k = i*9 + {0: base, 1+c: spline c}.
// ---------------------------------------------------------------------------
__global__ void pack_kan_w(const float* __restrict__ bw, const float* __restrict__ sw,
                           __hip_bfloat16* __restrict__ W, int K, int inShift,
                           size_t oBase, size_t total) {
  size_t t = (size_t)blockIdx.x * blockDim.x + threadIdx.x;
  if (t >= total) return;
  size_t o = t >> inShift;
  size_t i = t & (((size_t)1 << inShift) - 1);
  float b = bw[t];
  const float4* sp = (const float4*)(sw + t * 8);
  float4 s0 = sp[0], s1 = sp[1];
  __hip_bfloat16* dst = W + (oBase + o) * (size_t)K + i * NC;
  dst[0] = __float2bfloat16(b);
  dst[1] = __float2bfloat16(s0.x);
  dst[2] = __float2bfloat16(s0.y);
  dst[3] = __float2bfloat16(s0.z);
  dst[4] = __float2bfloat16(s0.w);
  dst[5] = __float2bfloat16(s1.x);
  dst[6] = __float2bfloat16(s1.y);
  dst[7] = __float2bfloat16(s1.z);
  dst[8] = __float2bfloat16(s1.w);
}

// A1(n, i*9+f) from x (NTOK x D_MODEL f32)
__global__ void build_a1(const float* __restrict__ x, __hip_bfloat16* __restrict__ A1) {
  size_t t = (size_t)blockIdx.x * blockDim.x + threadIdx.x;
  if (t >= (size_t)NTOK * D_MODEL) return;
  size_t n = t >> 10;
  size_t i = t & 1023;
  kan_feat(x[t], A1 + n * (size_t)K1 + i * NC);
}

// h = Hc[:, :4096] * Hc[:, 4096:]; A3c(n, j*9+f). Hc = one CHUNK of rows.
template <typename HT>
__global__ void glu_a3(const HT* __restrict__ Hc, __hip_bfloat16* __restrict__ A3c) {
  size_t t = (size_t)blockIdx.x * blockDim.x + threadIdx.x;
  if (t >= (size_t)CHUNK * D_FF) return;
  size_t n = t >> 12;
  size_t j = t & 4095;
  float h1, h2;
  if constexpr (std::is_same<HT, float>::value) {
    h1 = Hc[n * 8192 + j];
    h2 = Hc[n * 8192 + 4096 + j];
  } else {
    h1 = __bfloat162float(Hc[n * 8192 + j]);
    h2 = __bfloat162float(Hc[n * 8192 + 4096 + j]);
  }
  kan_feat(h1 * h2, A3c + n * (size_t)K3 + j * NC);
}

// ---------------------------------------------------------------------------
// bf16 GEMM, C = A (M x K, rm) * Bw^T (Bw: N x K, rm), CT out (f32 or bf16).
// 128x128 tile, 4 waves (2x2), BK=32, 16x16x32 MFMA, global_load_lds w=16.
// Split-K via blockIdx.z: slice z covers k in [z*kLen, (z+1)*kLen),
// writes partial C at Cp + z*M*N.
// ---------------------------------------------------------------------------
template <typename CT>
__global__ __launch_bounds__(256) void gemm_bt(
    const __hip_bfloat16* __restrict__ A, const __hip_bfloat16* __restrict__ Bw,
    CT* __restrict__ Cp, int N, int K, int kLen) {
  __shared__ __align__(16) __hip_bfloat16 As[128 * 32];
  __shared__ __align__(16) __hip_bfloat16 Bs[128 * 32];
  const int tid = threadIdx.x;
  const int wid = tid >> 6, lane = tid & 63;
  const int wr = wid >> 1, wc = wid & 1;
  const size_t brow = (size_t)blockIdx.y * 128;
  const size_t bcol = (size_t)blockIdx.x * 128;
  const int kStart = (int)blockIdx.z * kLen;
  const int kEnd = kStart + kLen;

  const int lrow = lane >> 2;        // row within 16-row chunk
  const int lcol = (lane & 3) * 8;   // k offset (8 bf16 = 16B)

  f32x4 acc[4][4] = {};

  for (int k0 = kStart; k0 < kEnd; k0 += 32) {
    __syncthreads();
#pragma unroll
    for (int s = 0; s < 2; ++s) {
      const int chunk = wid * 2 + s;  // 0..7, 16 rows each
      const __hip_bfloat16* ga = A + (brow + chunk * 16 + lrow) * (size_t)K + k0 + lcol;
      __builtin_amdgcn_global_load_lds((const __attribute__((address_space(1))) void*)ga,
                                       (__attribute__((address_space(3))) void*)(As + chunk * 512),
                                       16, 0, 0);
      const __hip_bfloat16* gb = Bw + (bcol + chunk * 16 + lrow) * (size_t)K + k0 + lcol;
      __builtin_amdgcn_global_load_lds((const __attribute__((address_space(1))) void*)gb,
                                       (__attribute__((address_space(3))) void*)(Bs + chunk * 512),
                                       16, 0, 0);
    }
    __syncthreads();  // drains vmcnt before LDS reads

    bf16x8 af[4], bfr[4];
#pragma unroll
    for (int mi = 0; mi < 4; ++mi)
      af[mi] = *(const bf16x8*)(As + (wr * 64 + mi * 16 + (lane & 15)) * 32 + (lane >> 4) * 8);
#pragma unroll
    for (int nj = 0; nj < 4; ++nj)
      bfr[nj] = *(const bf16x8*)(Bs + (wc * 64 + nj * 16 + (lane & 15)) * 32 + (lane >> 4) * 8);
#pragma unroll
    for (int mi = 0; mi < 4; ++mi)
#pragma unroll
      for (int nj = 0; nj < 4; ++nj)
        acc[mi][nj] = __builtin_amdgcn_mfma_f32_16x16x32_bf16(af[mi], bfr[nj], acc[mi][nj], 0, 0, 0);
  }

  const size_t M = (size_t)gridDim.y * 128;
  CT* C = Cp + (size_t)blockIdx.z * M * (size_t)N;
#pragma unroll
  for (int mi = 0; mi < 4; ++mi)
#pragma unroll
    for (int nj = 0; nj < 4; ++nj) {
      const int r0 = wr * 64 + mi * 16 + (lane >> 4) * 4;
      const int c0 = wc * 64 + nj * 16 + (lane & 15);
#pragma unroll
      for (int r = 0; r < 4; ++r) {
        float v = acc[mi][nj][r];
        if constexpr (std::is_same<CT, float>::value)
          C[(brow + r0 + r) * (size_t)N + bcol + c0] = v;
        else
          C[(brow + r0 + r) * (size_t)N + bcol + c0] = __float2bfloat16(v);
      }
    }
}

// sum SPLITK split-K partials (float4-vectorized); quarter = floats/4 per slice
__global__ void reduce8(const float* __restrict__ P, float* __restrict__ out, size_t quarter) {
  size_t t = (size_t)blockIdx.x * blockDim.x + threadIdx.x;
  if (t >= quarter) return;
  const float4* p = (const float4*)P;
  float4 a = p[t];
#pragma unroll
  for (int s = 1; s < SPLITK; ++s) {
    float4 b = p[(size_t)s * quarter + t];
    a.x += b.x; a.y += b.y; a.z += b.z; a.w += b.w;
  }
  ((float4*)out)[t] = a;
}

// ---------------------------------------------------------------------------
extern "C" void kernel_launch(void* const* d_in, const int* in_sizes, int n_in,
                              void* d_out, int out_size, void* d_ws, size_t ws_size,
                              hipStream_t stream) {
  const float* x   = (const float*)d_in[0];
  const float* bw1 = (const float*)d_in[1];
  const float* sw1 = (const float*)d_in[2];
  const float* bw2 = (const float*)d_in[3];
  const float* sw2 = (const float*)d_in[4];
  const float* bw3 = (const float*)d_in[5];
  const float* sw3 = (const float*)d_in[6];
  float* out = (float*)d_out;
  char* ws = (char*)d_ws;

  const size_t W12_B  = (size_t)8192 * K1 * 2;   // 150,994,944
  const size_t A1_B   = (size_t)NTOK * K1 * 2;   //  75,497,472
  const size_t A3C_B  = (size_t)CHUNK * K3 * 2;  //  75,497,472
  const size_t HF32_B = (size_t)NTOK * 8192 * 4; // 134,217,728

  // deterministic layout choice based only on ws_size
  const bool hF32 = ws_size >= W12_B + A1_B + HF32_B;  // 360,710,144

  __hip_bfloat16* W12 = (__hip_bfloat16*)(ws);
  __hip_bfloat16* A1  = (__hip_bfloat16*)(ws + W12_B);
  __hip_bfloat16* W3  = A1;                              // A1 dead after GEMM1
  void*           Hv  = (void*)(ws + W12_B + A1_B);
  __hip_bfloat16* A3c = (__hip_bfloat16*)(ws);           // W12 dead after GEMM1
  float*          Par = (float*)(ws + A3C_B);            // partials, 33.5MB

  // 1) pack W12 (w1 rows 0..4095, w2 rows 4096..8191)
  {
    size_t total = (size_t)D_FF * D_MODEL;
    int blocks = (int)((total + 255) / 256);
    pack_kan_w<<<blocks, 256, 0, stream>>>(bw1, sw1, W12, K1, 10, 0, total);
    pack_kan_w<<<blocks, 256, 0, stream>>>(bw2, sw2, W12, K1, 10, 4096, total);
  }
  // 2) build A1 from x
  {
    size_t total = (size_t)NTOK * D_MODEL;
    build_a1<<<(int)((total + 255) / 256), 256, 0, stream>>>(x, A1);
  }
  // 3) GEMM1: (4096 x 9216) x (8192 x 9216)^T -> H
  if (hF32)
    gemm_bt<float><<<dim3(8192 / 128, NTOK / 128, 1), 256, 0, stream>>>(
        A1, W12, (float*)Hv, 8192, K1, K1);
  else
    gemm_bt<__hip_bfloat16><<<dim3(8192 / 128, NTOK / 128, 1), 256, 0, stream>>>(
        A1, W12, (__hip_bfloat16*)Hv, 8192, K1, K1);
  // 4) pack W3 (into A1's region; A1 dead)
  {
    size_t total = (size_t)D_MODEL * D_FF;
    pack_kan_w<<<(int)((total + 255) / 256), 256, 0, stream>>>(bw3, sw3, W3, K3, 12, 0, total);
  }
  // 5) per-chunk: GLU+A3 build, GEMM2 split-K, reduce
  for (int c = 0; c < NTOK / CHUNK; ++c) {
    {
      size_t total = (size_t)CHUNK * D_FF;
      int blocks = (int)((total + 255) / 256);
      if (hF32)
        glu_a3<float><<<blocks, 256, 0, stream>>>(
            (const float*)Hv + (size_t)c * CHUNK * 8192, A3c);
      else
        glu_a3<__hip_bfloat16><<<blocks, 256, 0, stream>>>(
            (const __hip_bfloat16*)Hv + (size_t)c * CHUNK * 8192, A3c);
    }
    gemm_bt<float><<<dim3(D_MODEL / 128, CHUNK / 128, SPLITK), 256, 0, stream>>>(
        A3c, W3, Par, D_MODEL, K3, K3 / SPLITK);
    {
      size_t quarter = (size_t)CHUNK * D_MODEL / 4;
      reduce8<<<(int)((quarter + 255) / 256), 256, 0, stream>>>(
          Par, out + (size_t)c * CHUNK * D_MODEL, quarter);
    }
  }
}

// Round 3
// 1188.435 us; speedup vs baseline: 1.4532x; 1.4532x over previous
//
#include <hip/hip_runtime.h>
#include <hip/hip_bf16.h>
#include <cstdint>
#include <cstddef>
#include <type_traits>

// KAN GLU expert: h = kan(x;w1) * kan(x;w2); out = kan(h;w3)
// kan(x;W) == [silu(x_i), B0..B7(x_i)]_i @ [base_w | spline_w]^T
// -> bf16 MFMA GEMMs with K expanded 9x.
//
// GEMM: 256x256 tile, BK=32, ring-4 LDS slots (128 KB), counted vmcnt(8)
// pipeline (tile T+3 staged while computing tile T), swizzled LDS via
// pre-swizzled global source, XCD-aware block swizzle, setprio on MFMA.

#define D_MODEL 1024
#define D_FF    4096
#define NTOK    4096
#define NC      9
#define K1      (D_MODEL * NC)  // 9216
#define K3      (D_FF * NC)     // 36864
#define SPLITK2 16
#define CHUNK   1024

typedef __attribute__((ext_vector_type(8))) short bf16x8;
typedef __attribute__((ext_vector_type(4))) float f32x4;

// ---------------------------------------------------------------------------
// silu + 8 cubic B-spline bases on uniform grid t_m = 0.4*m - 2.2
// ---------------------------------------------------------------------------
__device__ __forceinline__ void kan_feat(float x, __hip_bfloat16* dst) {
  float s = x / (1.0f + __expf(-x));
  float B[11];
#pragma unroll
  for (int j = 0; j < 11; ++j) {
    float gj = -2.2f + 0.4f * j;
    B[j] = (x >= gj && x < gj + 0.4f) ? 1.0f : 0.0f;
  }
#pragma unroll
  for (int p = 1; p <= 3; ++p) {
    float inv = 1.0f / (0.4f * p);
#pragma unroll
    for (int i = 0; i + p < 11; ++i) {
      float gi = -2.2f + 0.4f * i;
      B[i] = (x - gi) * inv * B[i] + ((gi + 0.4f + 0.4f * p) - x) * inv * B[i + 1];
    }
  }
  dst[0] = __float2bfloat16(s);
#pragma unroll
  for (int c = 0; c < 8; ++c) dst[1 + c] = __float2bfloat16(B[c]);
}

// ---------------------------------------------------------------------------
__global__ void pack_kan_w(const float* __restrict__ bw, const float* __restrict__ sw,
                           __hip_bfloat16* __restrict__ W, int K, int inShift,
                           size_t oBase, size_t total) {
  size_t t = (size_t)blockIdx.x * blockDim.x + threadIdx.x;
  if (t >= total) return;
  size_t o = t >> inShift;
  size_t i = t & (((size_t)1 << inShift) - 1);
  float b = bw[t];
  const float4* sp = (const float4*)(sw + t * 8);
  float4 s0 = sp[0], s1 = sp[1];
  __hip_bfloat16* dst = W + (oBase + o) * (size_t)K + i * NC;
  dst[0] = __float2bfloat16(b);
  dst[1] = __float2bfloat16(s0.x);
  dst[2] = __float2bfloat16(s0.y);
  dst[3] = __float2bfloat16(s0.z);
  dst[4] = __float2bfloat16(s0.w);
  dst[5] = __float2bfloat16(s1.x);
  dst[6] = __float2bfloat16(s1.y);
  dst[7] = __float2bfloat16(s1.z);
  dst[8] = __float2bfloat16(s1.w);
}

__global__ void build_a1(const float* __restrict__ x, __hip_bfloat16* __restrict__ A1) {
  size_t t = (size_t)blockIdx.x * blockDim.x + threadIdx.x;
  if (t >= (size_t)NTOK * D_MODEL) return;
  size_t n = t >> 10;
  size_t i = t & 1023;
  kan_feat(x[t], A1 + n * (size_t)K1 + i * NC);
}

template <typename HT>
__global__ void glu_a3(const HT* __restrict__ Hc, __hip_bfloat16* __restrict__ A3c) {
  size_t t = (size_t)blockIdx.x * blockDim.x + threadIdx.x;
  if (t >= (size_t)CHUNK * D_FF) return;
  size_t n = t >> 12;
  size_t j = t & 4095;
  float h1, h2;
  if constexpr (std::is_same<HT, float>::value) {
    h1 = Hc[n * 8192 + j];
    h2 = Hc[n * 8192 + 4096 + j];
  } else {
    h1 = __bfloat162float(Hc[n * 8192 + j]);
    h2 = __bfloat162float(Hc[n * 8192 + 4096 + j]);
  }
  kan_feat(h1 * h2, A3c + n * (size_t)K3 + j * NC);
}

// ---------------------------------------------------------------------------
// 256x256 bf16 GEMM, C = A (M x K) * Bw^T (Bw: N x K), ring-4 pipelined.
// 512 thr = 8 waves (2M x 4N); per-wave 128x64 out = 8x4 f32x4 acc.
// LDS: 4 slots x (A 16KB + B 16KB). Slot holds one BK=32 K-tile.
// Swizzle: element (row, kb[16B grp]) at slot byte row*64 + (kb^((row>>1)&3))*16
//   -> ds_read_b128 frag reads are 2-way bank (free); staging writes linear,
//      global source pre-swizzled.
// Pipeline: iter T computes slot T%4, stages tile T+3 -> slot (T+3)%4
//   (prev occupant retired in iter T-1); steady wait vmcnt(8) (never drains).
// ---------------------------------------------------------------------------
#define STAGE(Ts)                                                                        \
  {                                                                                      \
    const int _sl = ((Ts) & 3) * 32768;                                                  \
    const size_t _ko = (size_t)(Ts) * 64;                                                \
    __builtin_amdgcn_global_load_lds(                                                    \
        (const __attribute__((address_space(1))) void*)(gA0 + _ko),                      \
        (__attribute__((address_space(3))) void*)(lds_raw + _sl + dA0), 16, 0, 0);       \
    __builtin_amdgcn_global_load_lds(                                                    \
        (const __attribute__((address_space(1))) void*)(gA1 + _ko),                      \
        (__attribute__((address_space(3))) void*)(lds_raw + _sl + dA1), 16, 0, 0);       \
    __builtin_amdgcn_global_load_lds(                                                    \
        (const __attribute__((address_space(1))) void*)(gB0 + _ko),                      \
        (__attribute__((address_space(3))) void*)(lds_raw + _sl + dB0), 16, 0, 0);       \
    __builtin_amdgcn_global_load_lds(                                                    \
        (const __attribute__((address_space(1))) void*)(gB1 + _ko),                      \
        (__attribute__((address_space(3))) void*)(lds_raw + _sl + dB1), 16, 0, 0);       \
  }

template <typename CT>
__global__ __launch_bounds__(512, 2) void gemm256(
    const __hip_bfloat16* __restrict__ A, const __hip_bfloat16* __restrict__ Bw,
    CT* __restrict__ Cp, int N, int K, int kLen) {
  __shared__ __align__(16) char lds_raw[4 * 32768];  // 128 KB

  const int tid = threadIdx.x;
  const int wid = tid >> 6, lane = tid & 63;
  const int wr = wid >> 2, wc = wid & 3;

  // bijective XCD swizzle (T1); both grids have nwg % 8 == 0
  const int nwg = gridDim.x * gridDim.y;
  const int orig = blockIdx.y * gridDim.x + blockIdx.x;
  const int q = nwg >> 3, r = nwg & 7;
  const int xcd = orig & 7, lid = orig >> 3;
  const int wg = (xcd < r ? xcd * (q + 1) : r * (q + 1) + (xcd - r) * q) + lid;
  const int bx = wg % gridDim.x, by = wg / gridDim.x;

  const size_t brow = (size_t)by * 256;
  const size_t bcol = (size_t)bx * 256;
  const int kStart = (int)blockIdx.z * kLen;
  const int NT = kLen / 32;

  // staging addressing: call-sites c=0,1 -> A halves; 2,3 -> B halves.
  // wave-issue (c,wid) covers rows (sub*8+wid)*16 + (lane>>2), 16B grp
  // kb = (lane&3) ^ ((lane>>3)&3) (pre-swizzled source).
  const int kbx = (lane & 3) ^ ((lane >> 3) & 3);
  const int rsub = lane >> 2;  // row within 16-row group
  const char* gA0 = (const char*)A +
      ((brow + (size_t)(wid * 16 + rsub)) * (size_t)K + kStart + kbx * 8) * 2;
  const char* gA1 = (const char*)A +
      ((brow + 128 + (size_t)(wid * 16 + rsub)) * (size_t)K + kStart + kbx * 8) * 2;
  const char* gB0 = (const char*)Bw +
      ((bcol + (size_t)(wid * 16 + rsub)) * (size_t)K + kStart + kbx * 8) * 2;
  const char* gB1 = (const char*)Bw +
      ((bcol + 128 + (size_t)(wid * 16 + rsub)) * (size_t)K + kStart + kbx * 8) * 2;
  const int dA0 = wid * 1024;
  const int dA1 = 8192 + wid * 1024;
  const int dB0 = 16384 + wid * 1024;
  const int dB1 = 24576 + wid * 1024;

  // ds_read fragment offsets (swizzled): frag (row, kb=lane>>4) at
  // row*64 + ((lane>>4) ^ ((row>>1)&3))*16;  row base multiple of 16 ->
  // ((row>>1)&3) == ((lane>>1)&3).
  const int fkb = (lane >> 4) ^ ((lane >> 1) & 3);
  const int aoff = (wr * 128 + (lane & 15)) * 64 + fkb * 16;
  const int boff = 16384 + (wc * 64 + (lane & 15)) * 64 + fkb * 16;

  f32x4 acc[8][4] = {};

  // prologue: stage tiles 0,1,2; ensure tile 0 landed (tiles 1,2 in flight)
  STAGE(0);
  STAGE(1);
  STAGE(2);
  asm volatile("s_waitcnt vmcnt(8)" ::: "memory");
  __builtin_amdgcn_s_barrier();

  for (int T = 0; T < NT; ++T) {
    if (T + 3 < NT) STAGE(T + 3);

    const int sl = (T & 3) * 32768;
    bf16x8 af[8], bfr[4];
#pragma unroll
    for (int mf = 0; mf < 8; ++mf)
      af[mf] = *(const bf16x8*)(lds_raw + sl + aoff + mf * 1024);
#pragma unroll
    for (int nf = 0; nf < 4; ++nf)
      bfr[nf] = *(const bf16x8*)(lds_raw + sl + boff + nf * 1024);

    __builtin_amdgcn_s_setprio(1);
#pragma unroll
    for (int mf = 0; mf < 8; ++mf)
#pragma unroll
      for (int nf = 0; nf < 4; ++nf)
        acc[mf][nf] =
            __builtin_amdgcn_mfma_f32_16x16x32_bf16(af[mf], bfr[nf], acc[mf][nf], 0, 0, 0);
    __builtin_amdgcn_s_setprio(0);

    // need tile T+1 landed before next iter; allow tiles T+2,T+3 in flight
    if (T + 4 <= NT) {
      asm volatile("s_waitcnt vmcnt(8)" ::: "memory");
    } else if (T + 3 == NT) {
      asm volatile("s_waitcnt vmcnt(4)" ::: "memory");
    } else if (T + 2 == NT) {
      asm volatile("s_waitcnt vmcnt(0)" ::: "memory");
    }
    if (T + 1 < NT) {
      asm volatile("s_waitcnt lgkmcnt(0)" ::: "memory");
      __builtin_amdgcn_s_barrier();
    }
  }

  // epilogue: C/D layout col=lane&15, row=(lane>>4)*4+r
#pragma unroll
  for (int mf = 0; mf < 8; ++mf)
#pragma unroll
    for (int nf = 0; nf < 4; ++nf) {
      const size_t r0 = brow + wr * 128 + mf * 16 + (lane >> 4) * 4;
      const size_t c0 = bcol + wc * 64 + nf * 16 + (lane & 15);
      const size_t M = (size_t)gridDim.y * 256;
      CT* C = Cp + (size_t)blockIdx.z * M * (size_t)N;
#pragma unroll
      for (int rr = 0; rr < 4; ++rr) {
        float v = acc[mf][nf][rr];
        if constexpr (std::is_same<CT, float>::value)
          C[(r0 + rr) * (size_t)N + c0] = v;
        else
          C[(r0 + rr) * (size_t)N + c0] = __float2bfloat16(v);
      }
    }
}

// sum SPLITK2 split-K partials (float4-vectorized)
__global__ void reduceK(const float* __restrict__ P, float* __restrict__ out, size_t quarter) {
  size_t t = (size_t)blockIdx.x * blockDim.x + threadIdx.x;
  if (t >= quarter) return;
  const float4* p = (const float4*)P;
  float4 a = p[t];
#pragma unroll
  for (int s = 1; s < SPLITK2; ++s) {
    float4 b = p[(size_t)s * quarter + t];
    a.x += b.x; a.y += b.y; a.z += b.z; a.w += b.w;
  }
  ((float4*)out)[t] = a;
}

// ---------------------------------------------------------------------------
extern "C" void kernel_launch(void* const* d_in, const int* in_sizes, int n_in,
                              void* d_out, int out_size, void* d_ws, size_t ws_size,
                              hipStream_t stream) {
  const float* x   = (const float*)d_in[0];
  const float* bw1 = (const float*)d_in[1];
  const float* sw1 = (const float*)d_in[2];
  const float* bw2 = (const float*)d_in[3];
  const float* sw2 = (const float*)d_in[4];
  const float* bw3 = (const float*)d_in[5];
  const float* sw3 = (const float*)d_in[6];
  float* out = (float*)d_out;
  char* ws = (char*)d_ws;

  const size_t W12_B  = (size_t)8192 * K1 * 2;   // 150,994,944
  const size_t A1_B   = (size_t)NTOK * K1 * 2;   //  75,497,472
  const size_t A3C_B  = (size_t)CHUNK * K3 * 2;  //  75,497,472
  const size_t HF32_B = (size_t)NTOK * 8192 * 4; // 134,217,728

  const bool hF32 = ws_size >= W12_B + A1_B + HF32_B;  // 360,710,144

  __hip_bfloat16* W12 = (__hip_bfloat16*)(ws);
  __hip_bfloat16* A1  = (__hip_bfloat16*)(ws + W12_B);
  __hip_bfloat16* W3  = A1;                              // A1 dead after GEMM1
  void*           Hv  = (void*)(ws + W12_B + A1_B);
  __hip_bfloat16* A3c = (__hip_bfloat16*)(ws);           // W12 dead after GEMM1
  float*          Par = (float*)(ws + A3C_B);            // 16x1024x1024 f32 = 67MB

  // 1) pack W12
  {
    size_t total = (size_t)D_FF * D_MODEL;
    int blocks = (int)((total + 255) / 256);
    pack_kan_w<<<blocks, 256, 0, stream>>>(bw1, sw1, W12, K1, 10, 0, total);
    pack_kan_w<<<blocks, 256, 0, stream>>>(bw2, sw2, W12, K1, 10, 4096, total);
  }
  // 2) build A1
  {
    size_t total = (size_t)NTOK * D_MODEL;
    build_a1<<<(int)((total + 255) / 256), 256, 0, stream>>>(x, A1);
  }
  // 3) GEMM1: (4096 x 9216) x (8192 x 9216)^T -> H
  if (hF32)
    gemm256<float><<<dim3(8192 / 256, NTOK / 256, 1), 512, 0, stream>>>(
        A1, W12, (float*)Hv, 8192, K1, K1);
  else
    gemm256<__hip_bfloat16><<<dim3(8192 / 256, NTOK / 256, 1), 512, 0, stream>>>(
        A1, W12, (__hip_bfloat16*)Hv, 8192, K1, K1);
  // 4) pack W3 (into A1's region)
  {
    size_t total = (size_t)D_MODEL * D_FF;
    pack_kan_w<<<(int)((total + 255) / 256), 256, 0, stream>>>(bw3, sw3, W3, K3, 12, 0, total);
  }
  // 5) per-chunk: GLU+A3 build, GEMM2 split-K=16, reduce
  for (int c = 0; c < NTOK / CHUNK; ++c) {
    {
      size_t total = (size_t)CHUNK * D_FF;
      int blocks = (int)((total + 255) / 256);
      if (hF32)
        glu_a3<float><<<blocks, 256, 0, stream>>>(
            (const float*)Hv + (size_t)c * CHUNK * 8192, A3c);
      else
        glu_a3<__hip_bfloat16><<<blocks, 256, 0, stream>>>(
            (const __hip_bfloat16*)Hv + (size_t)c * CHUNK * 8192, A3c);
    }
    gemm256<float><<<dim3(D_MODEL / 256, CHUNK / 256, SPLITK2), 512, 0, stream>>>(
        A3c, W3, Par, D_MODEL, K3, K3 / SPLITK2);
    {
      size_t quarter = (size_t)CHUNK * D_MODEL / 4;
      reduceK<<<(int)((quarter + 255) / 256), 256, 0, stream>>>(
          Par, out + (size_t)c * CHUNK * D_MODEL, quarter);
    }
  }
}

// Round 4
// 1184.352 us; speedup vs baseline: 1.4582x; 1.0034x over previous
//
#include <hip/hip_runtime.h>
#include <hip/hip_bf16.h>
#include <cstdint>
#include <cstddef>
#include <type_traits>

// KAN GLU expert: h = kan(x;w1) * kan(x;w2); out = kan(h;w3)
// kan(x;W) == [silu(x_i), B0..B7(x_i)]_i @ [base_w | spline_w]^T
// -> bf16 MFMA GEMMs with K expanded 9x.
//
// GEMM: 256x256 tile, BK=32, ring-4 LDS slots (128 KB), counted vmcnt(8)
// pipeline, 2 fine phases per K-tile (16 MFMA + dual barrier each, T3/T4),
// swizzled LDS via pre-swizzled global source (0 bank conflicts), XCD-aware
// block swizzle, setprio(1) on MFMA clusters (T5).

#define D_MODEL 1024
#define D_FF    4096
#define NTOK    4096
#define NC      9
#define K1      (D_MODEL * NC)  // 9216
#define K3      (D_FF * NC)     // 36864
#define SPLITK2 16
#define CHUNK   1024

typedef __attribute__((ext_vector_type(8))) short bf16x8;
typedef __attribute__((ext_vector_type(4))) float f32x4;

__device__ __forceinline__ unsigned short bf16b(float f) {
  __hip_bfloat16 h = __float2bfloat16(f);
  return __builtin_bit_cast(unsigned short, h);
}

// ---------------------------------------------------------------------------
// silu + 8 cubic B-spline bases on uniform grid t_m = 0.4*m - 2.2,
// written as 9 raw-bf16 ushorts.
// ---------------------------------------------------------------------------
__device__ __forceinline__ void kan_feat_u(float x, unsigned short* dst) {
  float s = x / (1.0f + __expf(-x));
  float B[11];
#pragma unroll
  for (int j = 0; j < 11; ++j) {
    float gj = -2.2f + 0.4f * j;
    B[j] = (x >= gj && x < gj + 0.4f) ? 1.0f : 0.0f;
  }
#pragma unroll
  for (int p = 1; p <= 3; ++p) {
    float inv = 1.0f / (0.4f * p);
#pragma unroll
    for (int i = 0; i + p < 11; ++i) {
      float gi = -2.2f + 0.4f * i;
      B[i] = (x - gi) * inv * B[i] + ((gi + 0.4f + 0.4f * p) - x) * inv * B[i + 1];
    }
  }
  dst[0] = bf16b(s);
#pragma unroll
  for (int c = 0; c < 8; ++c) dst[1 + c] = bf16b(B[c]);
}

// ---------------------------------------------------------------------------
// Pack two adjacent input-features per thread -> 9 dword stores (coalesced).
// ---------------------------------------------------------------------------
__global__ void pack_kan_w(const float* __restrict__ bw, const float* __restrict__ sw,
                           __hip_bfloat16* __restrict__ W, int K, int inShift,
                           size_t oBase, size_t totalPairs) {
  size_t t = (size_t)blockIdx.x * blockDim.x + threadIdx.x;
  if (t >= totalPairs) return;
  size_t o = t >> (inShift - 1);
  size_t ip = (t & (((size_t)1 << (inShift - 1)) - 1)) * 2;
  size_t e0 = (o << inShift) + ip;
  float2 b = *(const float2*)(bw + e0);
  const float4* sp = (const float4*)(sw + e0 * 8);
  float4 s0 = sp[0], s1 = sp[1], s2 = sp[2], s3 = sp[3];
  unsigned short h[18];
  h[0] = bf16b(b.x);
  h[1] = bf16b(s0.x); h[2] = bf16b(s0.y); h[3] = bf16b(s0.z); h[4] = bf16b(s0.w);
  h[5] = bf16b(s1.x); h[6] = bf16b(s1.y); h[7] = bf16b(s1.z); h[8] = bf16b(s1.w);
  h[9] = bf16b(b.y);
  h[10] = bf16b(s2.x); h[11] = bf16b(s2.y); h[12] = bf16b(s2.z); h[13] = bf16b(s2.w);
  h[14] = bf16b(s3.x); h[15] = bf16b(s3.y); h[16] = bf16b(s3.z); h[17] = bf16b(s3.w);
  uint32_t* dst = (uint32_t*)(W + (oBase + o) * (size_t)K + ip * NC);
#pragma unroll
  for (int k = 0; k < 9; ++k) dst[k] = (uint32_t)h[2 * k] | ((uint32_t)h[2 * k + 1] << 16);
}

// A1 from x; two elements per thread
__global__ void build_a1(const float* __restrict__ x, __hip_bfloat16* __restrict__ A1) {
  size_t t = (size_t)blockIdx.x * blockDim.x + threadIdx.x;
  if (t >= (size_t)NTOK * D_MODEL / 2) return;
  size_t n = t >> 9;               // 512 pairs per row
  size_t ip = (t & 511) * 2;
  float2 xv = *(const float2*)(x + n * D_MODEL + ip);
  unsigned short h[18];
  kan_feat_u(xv.x, h);
  kan_feat_u(xv.y, h + 9);
  uint32_t* dst = (uint32_t*)(A1 + n * (size_t)K1 + ip * NC);
#pragma unroll
  for (int k = 0; k < 9; ++k) dst[k] = (uint32_t)h[2 * k] | ((uint32_t)h[2 * k + 1] << 16);
}

// h = Hc[:, :4096] * Hc[:, 4096:]; two j per thread
template <typename HT>
__global__ void glu_a3(const HT* __restrict__ Hc, __hip_bfloat16* __restrict__ A3c) {
  size_t t = (size_t)blockIdx.x * blockDim.x + threadIdx.x;
  if (t >= (size_t)CHUNK * D_FF / 2) return;
  size_t n = t >> 11;              // 2048 pairs per row
  size_t jp = (t & 2047) * 2;
  float a0, a1, c0, c1;
  if constexpr (std::is_same<HT, float>::value) {
    float2 u = *(const float2*)(Hc + n * 8192 + jp);
    float2 v = *(const float2*)(Hc + n * 8192 + 4096 + jp);
    a0 = u.x; a1 = u.y; c0 = v.x; c1 = v.y;
  } else {
    a0 = __bfloat162float(Hc[n * 8192 + jp]);
    a1 = __bfloat162float(Hc[n * 8192 + jp + 1]);
    c0 = __bfloat162float(Hc[n * 8192 + 4096 + jp]);
    c1 = __bfloat162float(Hc[n * 8192 + 4096 + jp + 1]);
  }
  unsigned short h[18];
  kan_feat_u(a0 * c0, h);
  kan_feat_u(a1 * c1, h + 9);
  uint32_t* dst = (uint32_t*)(A3c + n * (size_t)K3 + jp * NC);
#pragma unroll
  for (int k = 0; k < 9; ++k) dst[k] = (uint32_t)h[2 * k] | ((uint32_t)h[2 * k + 1] << 16);
}

// ---------------------------------------------------------------------------
// 256x256 bf16 GEMM, C = A (M x K) * Bw^T (Bw: N x K), ring-4 pipelined,
// 2 fine phases per BK=32 tile.
// ---------------------------------------------------------------------------
#define STAGE_A(Ts)                                                                      \
  {                                                                                      \
    const int _sl = ((Ts) & 3) * 32768;                                                  \
    const size_t _ko = (size_t)(Ts) * 64;                                                \
    __builtin_amdgcn_global_load_lds(                                                    \
        (const __attribute__((address_space(1))) void*)(gA0 + _ko),                      \
        (__attribute__((address_space(3))) void*)(lds_raw + _sl + dA0), 16, 0, 0);       \
    __builtin_amdgcn_global_load_lds(                                                    \
        (const __attribute__((address_space(1))) void*)(gA1 + _ko),                      \
        (__attribute__((address_space(3))) void*)(lds_raw + _sl + dA1), 16, 0, 0);       \
  }
#define STAGE_B(Ts)                                                                      \
  {                                                                                      \
    const int _sl = ((Ts) & 3) * 32768;                                                  \
    const size_t _ko = (size_t)(Ts) * 64;                                                \
    __builtin_amdgcn_global_load_lds(                                                    \
        (const __attribute__((address_space(1))) void*)(gB0 + _ko),                      \
        (__attribute__((address_space(3))) void*)(lds_raw + _sl + dB0), 16, 0, 0);       \
    __builtin_amdgcn_global_load_lds(                                                    \
        (const __attribute__((address_space(1))) void*)(gB1 + _ko),                      \
        (__attribute__((address_space(3))) void*)(lds_raw + _sl + dB1), 16, 0, 0);       \
  }

template <typename CT>
__global__ __launch_bounds__(512, 2) void gemm256(
    const __hip_bfloat16* __restrict__ A, const __hip_bfloat16* __restrict__ Bw,
    CT* __restrict__ Cp, int N, int K, int kLen) {
  __shared__ __align__(16) char lds_raw[4 * 32768];  // 128 KB

  const int tid = threadIdx.x;
  const int wid = tid >> 6, lane = tid & 63;
  const int wr = wid >> 2, wc = wid & 3;

  // bijective XCD swizzle (T1); both grids have nwg % 8 == 0
  const int nwg = gridDim.x * gridDim.y;
  const int orig = blockIdx.y * gridDim.x + blockIdx.x;
  const int q = nwg >> 3, r = nwg & 7;
  const int xcd = orig & 7, lid = orig >> 3;
  const int wg = (xcd < r ? xcd * (q + 1) : r * (q + 1) + (xcd - r) * q) + lid;
  const int bx = wg % gridDim.x, by = wg / gridDim.x;

  const size_t brow = (size_t)by * 256;
  const size_t bcol = (size_t)bx * 256;
  const int kStart = (int)blockIdx.z * kLen;
  const int NT = kLen / 32;

  // staging: wave wid covers 16 rows of each half; 16B grp pre-swizzled
  const int kbx = (lane & 3) ^ ((lane >> 3) & 3);
  const int rsub = lane >> 2;
  const char* gA0 = (const char*)A +
      ((brow + (size_t)(wid * 16 + rsub)) * (size_t)K + kStart + kbx * 8) * 2;
  const char* gA1 = (const char*)A +
      ((brow + 128 + (size_t)(wid * 16 + rsub)) * (size_t)K + kStart + kbx * 8) * 2;
  const char* gB0 = (const char*)Bw +
      ((bcol + (size_t)(wid * 16 + rsub)) * (size_t)K + kStart + kbx * 8) * 2;
  const char* gB1 = (const char*)Bw +
      ((bcol + 128 + (size_t)(wid * 16 + rsub)) * (size_t)K + kStart + kbx * 8) * 2;
  const int dA0 = wid * 1024;
  const int dA1 = 8192 + wid * 1024;
  const int dB0 = 16384 + wid * 1024;
  const int dB1 = 24576 + wid * 1024;

  // ds_read fragment offsets (swizzled)
  const int fkb = (lane >> 4) ^ ((lane >> 1) & 3);
  const int aoff = (wr * 128 + (lane & 15)) * 64 + fkb * 16;
  const int boff = 16384 + (wc * 64 + (lane & 15)) * 64 + fkb * 16;

  f32x4 acc[8][4] = {};

  // prologue: stage tiles 0,1,2 (A then B per tile, FIFO), tile 0 landed
  STAGE_A(0); STAGE_B(0);
  STAGE_A(1); STAGE_B(1);
  STAGE_A(2); STAGE_B(2);
  asm volatile("s_waitcnt vmcnt(8)" ::: "memory");
  __builtin_amdgcn_s_barrier();

  for (int T = 0; T < NT; ++T) {
    const int sl = (T & 3) * 32768;

    // ---- phase 0: A rows 0..63 of wave tile + all B; MFMA quadrant mf0..3
    bf16x8 af0[4], bfr[4];
#pragma unroll
    for (int mf = 0; mf < 4; ++mf)
      af0[mf] = *(const bf16x8*)(lds_raw + sl + aoff + mf * 1024);
#pragma unroll
    for (int nf = 0; nf < 4; ++nf)
      bfr[nf] = *(const bf16x8*)(lds_raw + sl + boff + nf * 1024);
    if (T + 3 < NT) STAGE_A(T + 3);
    __builtin_amdgcn_s_barrier();
    asm volatile("s_waitcnt lgkmcnt(0)" ::: "memory");
    __builtin_amdgcn_sched_barrier(0);
    __builtin_amdgcn_s_setprio(1);
#pragma unroll
    for (int mf = 0; mf < 4; ++mf)
#pragma unroll
      for (int nf = 0; nf < 4; ++nf)
        acc[mf][nf] =
            __builtin_amdgcn_mfma_f32_16x16x32_bf16(af0[mf], bfr[nf], acc[mf][nf], 0, 0, 0);
    __builtin_amdgcn_s_setprio(0);
    __builtin_amdgcn_s_barrier();

    // ---- phase 1: A rows 64..127; MFMA quadrant mf4..7 (reuses bfr)
    bf16x8 af1[4];
#pragma unroll
    for (int mf = 0; mf < 4; ++mf)
      af1[mf] = *(const bf16x8*)(lds_raw + sl + aoff + (mf + 4) * 1024);
    if (T + 3 < NT) STAGE_B(T + 3);
    __builtin_amdgcn_s_barrier();
    asm volatile("s_waitcnt lgkmcnt(0)" ::: "memory");
    __builtin_amdgcn_sched_barrier(0);
    __builtin_amdgcn_s_setprio(1);
#pragma unroll
    for (int mf = 0; mf < 4; ++mf)
#pragma unroll
      for (int nf = 0; nf < 4; ++nf)
        acc[mf + 4][nf] =
            __builtin_amdgcn_mfma_f32_16x16x32_bf16(af1[mf], bfr[nf], acc[mf + 4][nf], 0, 0, 0);
    __builtin_amdgcn_s_setprio(0);

    // counted vmcnt once per tile: need tile T+1 landed before next iter
    if (T + 4 <= NT) {
      asm volatile("s_waitcnt vmcnt(8)" ::: "memory");
    } else if (T + 3 == NT) {
      asm volatile("s_waitcnt vmcnt(4)" ::: "memory");
    } else if (T + 2 == NT) {
      asm volatile("s_waitcnt vmcnt(0)" ::: "memory");
    }
    __builtin_amdgcn_s_barrier();
  }

  // epilogue: C/D layout col=lane&15, row=(lane>>4)*4+r
#pragma unroll
  for (int mf = 0; mf < 8; ++mf)
#pragma unroll
    for (int nf = 0; nf < 4; ++nf) {
      const size_t r0 = brow + wr * 128 + mf * 16 + (lane >> 4) * 4;
      const size_t c0 = bcol + wc * 64 + nf * 16 + (lane & 15);
      const size_t M = (size_t)gridDim.y * 256;
      CT* C = Cp + (size_t)blockIdx.z * M * (size_t)N;
#pragma unroll
      for (int rr = 0; rr < 4; ++rr) {
        float v = acc[mf][nf][rr];
        if constexpr (std::is_same<CT, float>::value)
          C[(r0 + rr) * (size_t)N + c0] = v;
        else
          C[(r0 + rr) * (size_t)N + c0] = __float2bfloat16(v);
      }
    }
}

// sum SPLITK2 split-K partials (float4-vectorized)
__global__ void reduceK(const float* __restrict__ P, float* __restrict__ out, size_t quarter) {
  size_t t = (size_t)blockIdx.x * blockDim.x + threadIdx.x;
  if (t >= quarter) return;
  const float4* p = (const float4*)P;
  float4 a = p[t];
#pragma unroll
  for (int s = 1; s < SPLITK2; ++s) {
    float4 b = p[(size_t)s * quarter + t];
    a.x += b.x; a.y += b.y; a.z += b.z; a.w += b.w;
  }
  ((float4*)out)[t] = a;
}

// ---------------------------------------------------------------------------
extern "C" void kernel_launch(void* const* d_in, const int* in_sizes, int n_in,
                              void* d_out, int out_size, void* d_ws, size_t ws_size,
                              hipStream_t stream) {
  const float* x   = (const float*)d_in[0];
  const float* bw1 = (const float*)d_in[1];
  const float* sw1 = (const float*)d_in[2];
  const float* bw2 = (const float*)d_in[3];
  const float* sw2 = (const float*)d_in[4];
  const float* bw3 = (const float*)d_in[5];
  const float* sw3 = (const float*)d_in[6];
  float* out = (float*)d_out;
  char* ws = (char*)d_ws;

  const size_t W12_B  = (size_t)8192 * K1 * 2;   // 150,994,944
  const size_t A1_B   = (size_t)NTOK * K1 * 2;   //  75,497,472
  const size_t A3C_B  = (size_t)CHUNK * K3 * 2;  //  75,497,472
  const size_t HF32_B = (size_t)NTOK * 8192 * 4; // 134,217,728

  const bool hF32 = ws_size >= W12_B + A1_B + HF32_B;  // 360,710,144

  __hip_bfloat16* W12 = (__hip_bfloat16*)(ws);
  __hip_bfloat16* A1  = (__hip_bfloat16*)(ws + W12_B);
  __hip_bfloat16* W3  = A1;                              // A1 dead after GEMM1
  void*           Hv  = (void*)(ws + W12_B + A1_B);
  __hip_bfloat16* A3c = (__hip_bfloat16*)(ws);           // W12 dead after GEMM1
  float*          Par = (float*)(ws + A3C_B);            // 16x1024x1024 f32

  // 1) pack W12
  {
    size_t pairs = (size_t)D_FF * D_MODEL / 2;
    int blocks = (int)((pairs + 255) / 256);
    pack_kan_w<<<blocks, 256, 0, stream>>>(bw1, sw1, W12, K1, 10, 0, pairs);
    pack_kan_w<<<blocks, 256, 0, stream>>>(bw2, sw2, W12, K1, 10, 4096, pairs);
  }
  // 2) build A1
  {
    size_t pairs = (size_t)NTOK * D_MODEL / 2;
    build_a1<<<(int)((pairs + 255) / 256), 256, 0, stream>>>(x, A1);
  }
  // 3) GEMM1: (4096 x 9216) x (8192 x 9216)^T -> H
  if (hF32)
    gemm256<float><<<dim3(8192 / 256, NTOK / 256, 1), 512, 0, stream>>>(
        A1, W12, (float*)Hv, 8192, K1, K1);
  else
    gemm256<__hip_bfloat16><<<dim3(8192 / 256, NTOK / 256, 1), 512, 0, stream>>>(
        A1, W12, (__hip_bfloat16*)Hv, 8192, K1, K1);
  // 4) pack W3 (into A1's region)
  {
    size_t pairs = (size_t)D_MODEL * D_FF / 2;
    pack_kan_w<<<(int)((pairs + 255) / 256), 256, 0, stream>>>(bw3, sw3, W3, K3, 12, 0, pairs);
  }
  // 5) per-chunk: GLU+A3 build, GEMM2 split-K=16, reduce
  for (int c = 0; c < NTOK / CHUNK; ++c) {
    {
      size_t pairs = (size_t)CHUNK * D_FF / 2;
      int blocks = (int)((pairs + 255) / 256);
      if (hF32)
        glu_a3<float><<<blocks, 256, 0, stream>>>(
            (const float*)Hv + (size_t)c * CHUNK * 8192, A3c);
      else
        glu_a3<__hip_bfloat16><<<blocks, 256, 0, stream>>>(
            (const __hip_bfloat16*)Hv + (size_t)c * CHUNK * 8192, A3c);
    }
    gemm256<float><<<dim3(D_MODEL / 256, CHUNK / 256, SPLITK2), 512, 0, stream>>>(
        A3c, W3, Par, D_MODEL, K3, K3 / SPLITK2);
    {
      size_t quarter = (size_t)CHUNK * D_MODEL / 4;
      reduceK<<<(int)((quarter + 255) / 256), 256, 0, stream>>>(
          Par, out + (size_t)c * CHUNK * D_MODEL, quarter);
    }
  }
}